// Round 3
// baseline (656.379 us; speedup 1.0000x reference)
//
#include <hip/hip_runtime.h>
#include <math.h>

// Problem constants
#define BSZ 8
#define LSEQ 8192
#define CONVD 192        // D_INNER + 2*D_STATE
#define NC 128           // chunks per sequence
#define PW 32            // pool window
#define LOG2E 1.4426950408889634f

// Per-dir workspace layout (in floats)
#define OFF_Z     0u          // 8*8192*64
#define OFF_DT    4194304u    // 8*8192*16
#define OFF_XBC   5242880u    // 8*8192*192
#define OFF_CT2   17825792u   // 8*16*8192
#define OFF_DST   18874368u   // 8*16*128*256
#define OFF_CHA   23068672u   // 8*16*128
#define OFF_YB    23085056u   // 8*8192*64
#define OFF_YS    27279360u   // 8*8192*16
#define OFF_PART  28327936u   // 256*32
#define OFF_COEF  28336128u   // 32
#define PD        28336160u   // floats per dir region

__device__ __forceinline__ float softplusf(float x) {
    return (x > 20.f) ? x : log1pf(expf(x));
}
__device__ __forceinline__ float siluf(float x) {
    return x / (1.f + expf(-x));
}

// DPP row_ror reduction over 16-lane rows.
template<int CTRL>
__device__ __forceinline__ float dpp_ror_add(float x) {
    int yi = __builtin_amdgcn_update_dpp(0, __float_as_int(x), CTRL, 0xf, 0xf, false);
    return x + __int_as_float(yi);
}
__device__ __forceinline__ float rowsum16(float x) {
    x = dpp_ror_add<0x128>(x);
    x = dpp_ror_add<0x124>(x);
    x = dpp_ror_add<0x122>(x);
    x = dpp_ror_add<0x121>(x);
    return x;
}

// XOR-quad swizzle for [64][64] LDS tiles.
#define SWZQ(row, c4) (((((c4) >> 2) ^ ((row) >> 2)) & 15) << 2)

// ---------------------------------------------------------------------------
// K_FRONT: fused in-proj + depthwise conv (register shift) + silu
//          + per-chunk scan (ct2, chunkA) + chunk state delta Dst.
// block = (ck, b, dirz), 320 threads; thread = output column p (272 active).
// ---------------------------------------------------------------------------
__global__ __launch_bounds__(320) void k_front(
    const float* __restrict__ x, const float* __restrict__ Win,
    const float* __restrict__ convw, const float* __restrict__ convb,
    const float* __restrict__ dtb, const float* __restrict__ A_log,
    float* __restrict__ ws, int dir0, int dslm)
{
    __shared__ float u_s[67 * 16];   // [pos][c], pos -> l = l0+pos-3
    __shared__ float xh_s[4096];     // [t][d]  (post conv+silu), then wx
    __shared__ float Bs[4096];       // [t][n]
    __shared__ float wbuf[16 * 66];  // [h][t]  exp2(tot-ct)*dt
    __shared__ float dts[16 * 66];   // [h][t]
    const int tid = threadIdx.x;
    const int ck = blockIdx.x;
    const int b = blockIdx.y;
    const int dir = dir0 + blockIdx.z;
    float* base = ws + (size_t)(dslm * blockIdx.z) * PD;
    float* z_buf  = base + OFF_Z;
    float* dt_buf = base + OFF_DT;
    float* xbc    = base + OFF_XBC;
    float* ct2    = base + OFF_CT2;
    float* Dst    = base + OFF_DST;
    float* chA    = base + OFF_CHA;
    const int l0 = ck * 64;

    // stage u (67 positions with 3-halo; zero for l<0)
    for (int i = tid; i < 67 * 16; i += 320) {
        int pos = i >> 4, c = i & 15;
        int l = l0 + pos - 3;
        float v = 0.f;
        if (l >= 0) {
            if (dir == 0) {
                v = x[(b * 16 + c) * 8192 + l];
            } else if (dir == 1) {
                int h = l >> 9, w = (l >> 5) & 15, d = l & 31;
                v = x[(((b * 16 + c) * 32 + d) * 16 + h) * 16 + w];
            } else {
                int w = l >> 9, d = (l >> 4) & 31, h = l & 15;
                v = x[(((b * 16 + c) * 32 + d) * 16 + h) * 16 + w];
            }
        }
        u_s[i] = v;
    }

    // per-thread weights in registers
    float4 w0, w1, w2, w3;
    float4 cwv; float cbv = 0.f, bias = 0.f;
    const int ch = tid - 64;
    if (tid < 272) {
        const float* wp = Win + (size_t)(dir * 272 + tid) * 16;
        w0 = *(const float4*)(wp);
        w1 = *(const float4*)(wp + 4);
        w2 = *(const float4*)(wp + 8);
        w3 = *(const float4*)(wp + 12);
    }
    if (tid >= 64 && tid < 256) {
        cwv = *(const float4*)(convw + (size_t)(dir * CONVD + ch) * 4);
        cbv = convb[dir * CONVD + ch];
    } else if (tid >= 256 && tid < 272) {
        bias = dtb[dir * 16 + (tid - 256)];
    }
    __syncthreads();

    // main position loop: dot(u,w) + register-shift conv
    float v0 = 0.f, v1 = 0.f, v2 = 0.f, v3 = 0.f;
    #pragma unroll 4
    for (int pos = 0; pos < 67; ++pos) {
        const float4* up = (const float4*)&u_s[pos * 16];
        float4 u0 = up[0], u1 = up[1], u2 = up[2], u3 = up[3];
        float acc = u0.x * w0.x + u0.y * w0.y + u0.z * w0.z + u0.w * w0.w
                  + u1.x * w1.x + u1.y * w1.y + u1.z * w1.z + u1.w * w1.w
                  + u2.x * w2.x + u2.y * w2.y + u2.z * w2.z + u2.w * w2.w
                  + u3.x * w3.x + u3.y * w3.y + u3.z * w3.z + u3.w * w3.w;
        v0 = v1; v1 = v2; v2 = v3; v3 = acc;
        if (pos >= 3) {
            int t = pos - 3;
            size_t bl = (size_t)(b * 8192 + l0 + t);
            if (tid < 64) {
                z_buf[bl * 64 + tid] = acc;
            } else if (tid < 256) {
                float cv = cbv + cwv.x * v0 + cwv.y * v1 + cwv.z * v2 + cwv.w * v3;
                float xv = siluf(cv);
                xbc[bl * CONVD + ch] = xv;
                if (ch < 64) xh_s[t * 64 + ch] = xv;
                else if (ch < 128) Bs[t * 64 + (ch - 64)] = xv;
            } else if (tid < 272) {
                float dv = softplusf(acc + bias);
                dt_buf[bl * 16 + (tid - 256)] = dv;
                dts[(tid - 256) * 66 + t] = dv;
            }
        }
    }
    __syncthreads();

    // per-head cumulative log2-decay scan
    const int wave = tid >> 6;
    const int lane = tid & 63;
    if (wave < 4) {
        for (int h = wave; h < 16; h += 4) {
            float A2 = -expf(A_log[dir * 16 + h]) * LOG2E;
            float dtv = dts[h * 66 + lane];
            float v = dtv * A2;
            #pragma unroll
            for (int off = 1; off < 64; off <<= 1) {
                float o = __shfl_up(v, off, 64);
                if (lane >= off) v += o;
            }
            float tot = __shfl(v, 63, 64);
            ct2[(b * 16 + h) * 8192 + l0 + lane] = v;
            wbuf[h * 66 + lane] = exp2f(tot - v) * dtv;
            if (lane == 63) chA[(b * 16 + h) * 128 + ck] = exp2f(tot);
        }
    }
    __syncthreads();

    // wx[t][hp] = wbuf[h][t] * xh[t][hp]
    for (int i = tid; i < 4096; i += 320) {
        int t = i >> 6, hp = i & 63;
        xh_s[i] *= wbuf[(hp >> 2) * 66 + t];
    }
    __syncthreads();

    // Dst[hp][n] = sum_t wx[t][hp] * B[t][n], register-tiled 4x4
    if (tid < 256) {
        const int hp4 = tid >> 4;
        const int n4 = tid & 15;
        float a[4][4] = {};
        #pragma unroll 8
        for (int t = 0; t < 64; t++) {
            float4 wv = *(const float4*)&xh_s[t * 64 + 4 * hp4];
            float4 bv = *(const float4*)&Bs[t * 64 + 4 * n4];
            a[0][0] += wv.x * bv.x; a[0][1] += wv.x * bv.y; a[0][2] += wv.x * bv.z; a[0][3] += wv.x * bv.w;
            a[1][0] += wv.y * bv.x; a[1][1] += wv.y * bv.y; a[1][2] += wv.y * bv.z; a[1][3] += wv.y * bv.w;
            a[2][0] += wv.z * bv.x; a[2][1] += wv.z * bv.y; a[2][2] += wv.z * bv.z; a[2][3] += wv.z * bv.w;
            a[3][0] += wv.w * bv.x; a[3][1] += wv.w * bv.y; a[3][2] += wv.w * bv.z; a[3][3] += wv.w * bv.w;
        }
        #pragma unroll
        for (int i = 0; i < 4; i++) {
            int hp = 4 * hp4 + i;
            int h = hp >> 2, p = hp & 3;
            float4 o = make_float4(a[i][0], a[i][1], a[i][2], a[i][3]);
            *(float4*)(Dst + ((size_t)((b * 16 + h) * 128 + ck)) * 256 + p * 64 + 4 * n4) = o;
        }
    }
}

// ---------------------------------------------------------------------------
// K3: inter-chunk scan (sequential over 128 chunks), in place.
// ---------------------------------------------------------------------------
__global__ __launch_bounds__(256) void k_chunk_scan(
    float* __restrict__ ws, int dslm)
{
    float* base = ws + (size_t)(dslm * blockIdx.z) * PD;
    float* Dst = base + OFF_DST;
    const float* chA = base + OFF_CHA;
    const int bh = blockIdx.x;
    const int tid = threadIdx.x;
    float S = 0.f;
    for (int k0 = 0; k0 < NC; k0 += 8) {
        float d[8], av[8];
        #pragma unroll
        for (int j = 0; j < 8; j++) {
            d[j] = Dst[((size_t)(bh * 128 + k0 + j)) * 256 + tid];
            av[j] = chA[bh * 128 + k0 + j];
        }
        #pragma unroll
        for (int j = 0; j < 8; j++) {
            Dst[((size_t)(bh * 128 + k0 + j)) * 256 + tid] = S;
            S = av[j] * S + d[j];
        }
    }
}

// ---------------------------------------------------------------------------
// K4: chunk output, register-tiled (unchanged logic from round 2).
// ---------------------------------------------------------------------------
__global__ __launch_bounds__(256, 3) void k_chunk_out(
    float* __restrict__ ws, int dslm)
{
    float* base = ws + (size_t)(dslm * blockIdx.z) * PD;
    const float* xbc     = base + OFF_XBC;
    const float* dt_buf  = base + OFF_DT;
    const float* ct2_buf = base + OFF_CT2;
    const float* Dst     = base + OFF_DST;
    float* ybuf          = base + OFF_YB;

    __shared__ float Cs[4096];
    __shared__ float Bx[4096];
    __shared__ float Sn[4096];
    __shared__ float ct2s[16 * 66];
    const int tid = threadIdx.x;
    const int b = blockIdx.y;
    const int ck = blockIdx.x;
    const int l0 = ck * 64;
    const int t4 = tid >> 4;
    const int x4 = tid & 15;

    for (int i = tid; i < 1024; i += 256) {
        int r = i >> 4, c4 = (i & 15) << 2;
        const float* row = xbc + (size_t)(b * 8192 + l0 + r) * CONVD;
        float4 bv = *(const float4*)(row + 64 + c4);
        float4 cv = *(const float4*)(row + 128 + c4);
        int qb = SWZQ(r, c4);
        *(float4*)&Bx[r * 64 + qb] = bv;
        *(float4*)&Cs[r * 64 + qb] = cv;
    }
    for (int i = tid; i < 1024; i += 256) {
        int hp = i >> 4, n4 = (i & 15) << 2;
        int h = hp >> 2, p = hp & 3;
        float4 sv = *(const float4*)(Dst + ((size_t)((b * 16 + h) * 128 + ck)) * 256 + p * 64 + n4);
        *(float4*)&Sn[hp * 64 + SWZQ(hp, n4)] = sv;
    }
    for (int i = tid; i < 1024; i += 256) {
        int h = i >> 6, t = i & 63;
        ct2s[h * 66 + t] = ct2_buf[(b * 16 + h) * 8192 + l0 + t];
    }
    __syncthreads();

    float G_[4][4] = {}, CS_[4][4] = {};
    #pragma unroll 4
    for (int nt = 0; nt < 16; nt++) {
        float4 cr[4], br[4], sr[4];
        #pragma unroll
        for (int r = 0; r < 4; r++) {
            cr[r] = *(const float4*)&Cs[(4 * t4 + r) * 64 + (((nt ^ t4) & 15) << 2)];
            br[r] = *(const float4*)&Bx[(4 * x4 + r) * 64 + (((nt ^ x4) & 15) << 2)];
            sr[r] = *(const float4*)&Sn[(4 * x4 + r) * 64 + (((nt ^ x4) & 15) << 2)];
        }
        #pragma unroll
        for (int r = 0; r < 4; r++)
            #pragma unroll
            for (int q = 0; q < 4; q++) {
                G_[r][q] += cr[r].x * br[q].x + cr[r].y * br[q].y
                          + cr[r].z * br[q].z + cr[r].w * br[q].w;
                CS_[r][q] += cr[r].x * sr[q].x + cr[r].y * sr[q].y
                           + cr[r].z * sr[q].z + cr[r].w * sr[q].w;
            }
    }
    __syncthreads();

    for (int i = tid; i < 1024; i += 256) {
        int r = i >> 4, c4 = (i & 15) << 2;
        const float* row = xbc + (size_t)(b * 8192 + l0 + r) * CONVD;
        float4 xv = *(const float4*)(row + c4);
        float dtv = dt_buf[(size_t)(b * 8192 + l0 + r) * 16 + (c4 >> 2)];
        xv.x *= dtv; xv.y *= dtv; xv.z *= dtv; xv.w *= dtv;
        *(float4*)&Bx[r * 64 + SWZQ(r, c4)] = xv;
    }
    __syncthreads();

    const int tbase = 4 * t4;
    #pragma unroll 1
    for (int h = 0; h < 16; h++) {
        float ctt[4], ect[4];
        #pragma unroll
        for (int r = 0; r < 4; r++) {
            ctt[r] = ct2s[h * 66 + tbase + r];
            ect[r] = exp2f(ctt[r]);
        }
        float acc[4][4] = {};
        #pragma unroll
        for (int q = 0; q < 4; q++) {
            int s = 4 * x4 + q;
            float cs_ = ct2s[h * 66 + s];
            float4 xdv = *(const float4*)&Bx[s * 64 + (((h ^ x4) & 15) << 2)];
            #pragma unroll
            for (int r = 0; r < 4; r++) {
                float e = exp2f(ctt[r] - cs_);
                e = (s <= tbase + r) ? e : 0.f;
                float ge = G_[r][q] * e;
                acc[r][0] += ge * xdv.x; acc[r][1] += ge * xdv.y;
                acc[r][2] += ge * xdv.z; acc[r][3] += ge * xdv.w;
            }
        }
        if (x4 == h) {
            #pragma unroll
            for (int r = 0; r < 4; r++)
                #pragma unroll
                for (int p = 0; p < 4; p++)
                    acc[r][p] += ect[r] * CS_[r][p];
        }
        #pragma unroll
        for (int r = 0; r < 4; r++)
            #pragma unroll
            for (int p = 0; p < 4; p++)
                acc[r][p] = rowsum16(acc[r][p]);
        float out = acc[0][0];
        #pragma unroll
        for (int r = 0; r < 4; r++)
            #pragma unroll
            for (int p = 0; p < 4; p++)
                if (r || p)
                    out = (x4 == r * 4 + p) ? acc[r][p] : out;
        int rr = x4 >> 2, pp = x4 & 3;
        ybuf[(size_t)(b * 8192 + l0 + tbase + rr) * 64 + h * 4 + pp] = out;
    }
}

// ---------------------------------------------------------------------------
// K5: epilogue: y += Dp*xh ; gate silu(z); RMSNorm(*norm_w); out-proj -> ys
// ---------------------------------------------------------------------------
__global__ __launch_bounds__(256) void k_epilogue(
    float* __restrict__ ws, const float* __restrict__ Dp,
    const float* __restrict__ normw, const float* __restrict__ Wout,
    int dir0, int dslm)
{
    float* base = ws + (size_t)(dslm * blockIdx.z) * PD;
    const float* ybuf  = base + OFF_YB;
    const float* xbc   = base + OFF_XBC;
    const float* z_buf = base + OFF_Z;
    float* ys          = base + OFF_YS;
    const int dir = dir0 + blockIdx.z;

    __shared__ float WoutN[16 * 64];
    __shared__ float Dps[16];
    const int tid = threadIdx.x;
    for (int idx = tid; idx < 1024; idx += 256)
        WoutN[idx] = Wout[dir * 1024 + idx] * normw[dir * 64 + (idx & 63)];
    if (tid < 16) Dps[tid] = Dp[dir * 16 + tid];
    __syncthreads();

    const int b = blockIdx.y;
    const int tile = blockIdx.x;
    const int t = tid >> 2;
    const int q = tid & 3;
    const int l = tile * 64 + t;
    const size_t bl = (size_t)(b * 8192 + l);

    float g[16];
    float sumsq = 0.f;
    #pragma unroll
    for (int k = 0; k < 4; k++) {
        float4 y4 = *(const float4*)(ybuf + bl * 64 + q * 16 + 4 * k);
        float4 x4v = *(const float4*)(xbc + bl * CONVD + q * 16 + 4 * k);
        float4 z4 = *(const float4*)(z_buf + bl * 64 + q * 16 + 4 * k);
        int h = (q * 16 + 4 * k) >> 2;
        float dpv = Dps[h];
        float vv0 = (y4.x + dpv * x4v.x) * siluf(z4.x);
        float vv1 = (y4.y + dpv * x4v.y) * siluf(z4.y);
        float vv2 = (y4.z + dpv * x4v.z) * siluf(z4.z);
        float vv3 = (y4.w + dpv * x4v.w) * siluf(z4.w);
        g[4 * k] = vv0; g[4 * k + 1] = vv1; g[4 * k + 2] = vv2; g[4 * k + 3] = vv3;
        sumsq += vv0 * vv0 + vv1 * vv1 + vv2 * vv2 + vv3 * vv3;
    }
    sumsq += __shfl_xor(sumsq, 1);
    sumsq += __shfl_xor(sumsq, 2);
    float rms = rsqrtf(sumsq * (1.f / 64.f) + 1e-5f);

    float oc[16];
    #pragma unroll
    for (int c = 0; c < 16; c++) {
        float a = 0.f;
        #pragma unroll
        for (int i = 0; i < 16; i++) a += g[i] * WoutN[c * 64 + q * 16 + i];
        oc[c] = a;
    }
    #pragma unroll
    for (int c = 0; c < 16; c++) {
        oc[c] += __shfl_xor(oc[c], 1);
        oc[c] += __shfl_xor(oc[c], 2);
    }
    float4 o4 = make_float4(oc[q * 4] * rms, oc[q * 4 + 1] * rms,
                            oc[q * 4 + 2] * rms, oc[q * 4 + 3] * rms);
    *(float4*)(ys + bl * 16 + q * 4) = o4;
}

// ---------------------------------------------------------------------------
// K6a: BN batch stats, deterministic two-stage.
// ---------------------------------------------------------------------------
__global__ __launch_bounds__(256) void k_bnstats(
    float* __restrict__ ws, int dslm)
{
    float* base = ws + (size_t)(dslm * blockIdx.z) * PD;
    const float* ys = base + OFF_YS;
    float* partials = base + OFF_PART;
    const int tid = threadIdx.x;
    const int r = blockIdx.x * 256 + tid;
    float s[16], qv[16];
    const float* row = ys + (size_t)r * 16;
    #pragma unroll
    for (int k = 0; k < 4; k++) {
        float4 v4 = *(const float4*)(row + 4 * k);
        float vv0 = fmaxf(v4.x, 0.f), vv1 = fmaxf(v4.y, 0.f);
        float vv2 = fmaxf(v4.z, 0.f), vv3 = fmaxf(v4.w, 0.f);
        s[4 * k] = vv0; s[4 * k + 1] = vv1; s[4 * k + 2] = vv2; s[4 * k + 3] = vv3;
        qv[4 * k] = vv0 * vv0; qv[4 * k + 1] = vv1 * vv1;
        qv[4 * k + 2] = vv2 * vv2; qv[4 * k + 3] = vv3 * vv3;
    }
    #pragma unroll
    for (int off = 1; off < 64; off <<= 1) {
        #pragma unroll
        for (int c = 0; c < 16; c++) {
            s[c] += __shfl_xor(s[c], off);
            qv[c] += __shfl_xor(qv[c], off);
        }
    }
    __shared__ float red[4][32];
    const int wave = tid >> 6, lane = tid & 63;
    if (lane == 0) {
        #pragma unroll
        for (int c = 0; c < 16; c++) {
            red[wave][c] = s[c];
            red[wave][16 + c] = qv[c];
        }
    }
    __syncthreads();
    if (tid < 32) {
        float a = red[0][tid] + red[1][tid] + red[2][tid] + red[3][tid];
        partials[blockIdx.x * 32 + tid] = a;
    }
}

// K6b: final reduce + fold BN affine + linear into coefs
__global__ __launch_bounds__(256) void k_bnreduce(
    float* __restrict__ ws, const float* __restrict__ gamma,
    const float* __restrict__ beta, const float* __restrict__ lin_w,
    const float* __restrict__ lin_b, int dir0, int dslm)
{
    float* base = ws + (size_t)(dslm * blockIdx.z) * PD;
    const float* partials = base + OFF_PART;
    float* coefs = base + OFF_COEF;
    const int dir = dir0 + blockIdx.z;

    __shared__ float S[32];
    __shared__ float mu_s[16], coef_s[16];
    const int tid = threadIdx.x;
    if (tid < 32) {
        float a = 0.f;
        for (int k = 0; k < 256; k++) a += partials[k * 32 + tid];
        S[tid] = a;
    }
    __syncthreads();
    if (tid < 16) {
        float mu = S[tid] * (1.f / 65536.f);
        float var = S[16 + tid] * (1.f / 65536.f) - mu * mu;
        float inv = rsqrtf(var + 1e-5f);
        float coef = inv * gamma[dir * 16 + tid] * lin_w[dir * 16 + tid];
        mu_s[tid] = mu;
        coef_s[tid] = coef;
        coefs[tid] = coef;
    }
    __syncthreads();
    if (tid == 0) {
        float off = lin_b[dir];
        for (int c = 0; c < 16; c++)
            off += beta[dir * 16 + c] * lin_w[dir * 16 + c] - mu_s[c] * coef_s[c];
        coefs[16] = off;
    }
}

// K7: fused BN-apply + linear + maxpool(32).
__global__ __launch_bounds__(256) void k_pool(
    float* __restrict__ ws, float* __restrict__ out, int dir0, int dslm)
{
    float* base = ws + (size_t)(dslm * blockIdx.z) * PD;
    const float* ys = base + OFF_YS;
    const float* coefs = base + OFF_COEF;
    const int dir = dir0 + blockIdx.z;

    __shared__ float cf[17];
    const int tid = threadIdx.x;
    if (tid < 17) cf[tid] = coefs[tid];
    __syncthreads();
    const int b = blockIdx.x >> 3;
    const int jg = blockIdx.x & 7;
    const int j = jg * 32 + (tid >> 3);
    const int sub = tid & 7;
    float m = -3.4e38f;
    #pragma unroll
    for (int r = 0; r < 4; r++) {
        int l = j * PW + 8 * r + sub;
        const float* row = ys + (size_t)(b * 8192 + l) * 16;
        float sv = cf[16];
        #pragma unroll
        for (int k = 0; k < 4; k++) {
            float4 v4 = *(const float4*)(row + 4 * k);
            sv += fmaxf(v4.x, 0.f) * cf[4 * k] + fmaxf(v4.y, 0.f) * cf[4 * k + 1]
                + fmaxf(v4.z, 0.f) * cf[4 * k + 2] + fmaxf(v4.w, 0.f) * cf[4 * k + 3];
        }
        m = fmaxf(m, sv);
    }
    m = fmaxf(m, __shfl_xor(m, 1));
    m = fmaxf(m, __shfl_xor(m, 2));
    m = fmaxf(m, __shfl_xor(m, 4));
    if (sub == 0) out[b * 768 + dir * 256 + j] = m;
}

// ---------------------------------------------------------------------------
extern "C" void kernel_launch(void* const* d_in, const int* in_sizes, int n_in,
                              void* d_out, int out_size, void* d_ws, size_t ws_size,
                              hipStream_t stream) {
    const float* x     = (const float*)d_in[0];
    const float* Win   = (const float*)d_in[1];
    const float* convw = (const float*)d_in[2];
    const float* convb = (const float*)d_in[3];
    const float* dtb   = (const float*)d_in[4];
    const float* Alog  = (const float*)d_in[5];
    const float* Dp    = (const float*)d_in[6];
    const float* normw = (const float*)d_in[7];
    const float* Wout  = (const float*)d_in[8];
    const float* gamma = (const float*)d_in[9];
    const float* beta  = (const float*)d_in[10];
    const float* linw  = (const float*)d_in[11];
    const float* linb  = (const float*)d_in[12];
    float* out = (float*)d_out;
    float* ws = (float*)d_ws;

    const bool batched = ws_size >= (size_t)3 * PD * 4;
    const int nz = batched ? 3 : 1;
    const int dslm = batched ? 1 : 0;
    const int nloop = batched ? 1 : 3;

    for (int d0 = 0; d0 < nloop; ++d0) {
        k_front<<<dim3(128, 8, nz), dim3(320), 0, stream>>>(
            x, Win, convw, convb, dtb, Alog, ws, d0, dslm);
        k_chunk_scan<<<dim3(128, 1, nz), dim3(256), 0, stream>>>(ws, dslm);
        k_chunk_out<<<dim3(128, 8, nz), dim3(256), 0, stream>>>(ws, dslm);
        k_epilogue<<<dim3(128, 8, nz), dim3(256), 0, stream>>>(
            ws, Dp, normw, Wout, d0, dslm);
        k_bnstats<<<dim3(256, 1, nz), dim3(256), 0, stream>>>(ws, dslm);
        k_bnreduce<<<dim3(1, 1, nz), dim3(256), 0, stream>>>(
            ws, gamma, beta, linw, linb, d0, dslm);
        k_pool<<<dim3(64, 1, nz), dim3(256), 0, stream>>>(ws, out, d0, dslm);
    }
}